// Round 6
// baseline (8514.475 us; speedup 1.0000x reference)
//
#include <hip/hip_runtime.h>
#include <cstdint>
#include <cmath>

#define BATCH 1024
#define SEQ   100
#define HD    256
#define HD3   768

__device__ __forceinline__ float sigmoidf_(float x) { return 1.0f / (1.0f + expf(-x)); }

// GRU cell with h=0: out = (1-z)*n ; gh == b_hh (constant)
__device__ __forceinline__ float gru0(float gr, float gz, float gn, float hr, float hz, float hn) {
    float r = sigmoidf_(gr + hr);
    float z = sigmoidf_(gz + hz);
    float n = tanhf(gn + r * hn);
    return (1.0f - z) * n;
}

// ---------------- init: mean over N of encoder rows ----------------
__global__ __launch_bounds__(256) void init_mean_kernel(const float* __restrict__ enc,
                                                        float* __restrict__ meanenc) {
    int b = blockIdx.x, tid = threadIdx.x;
    const float* e = enc + (size_t)b * SEQ * HD + tid;
    float s = 0.f;
    for (int n = 0; n < SEQ; ++n) s += e[(size_t)n * HD];
    meanenc[(size_t)b * HD + tid] = s * (1.0f / SEQ);
}

// ---- prep: per-thread float4 weight packs + wl + zero bias ----
// W1p4[k*256+t] = (W_ih1[t][k], W_ih1[t+256][k], W_ih1[t+512][k], 0)   (W_ih1 ld=257)
// W2p4[k*256+t] = (W_ih2[t][k], W_ih2[t+256][k], W_ih2[t+512][k], 0)   (W_ih2 ld=256)
__global__ __launch_bounds__(256) void prep_kernel(const float* __restrict__ W_ih1,
                                                   const float* __restrict__ W_ih2,
                                                   float4* __restrict__ W1p4,
                                                   float4* __restrict__ W2p4,
                                                   float* __restrict__ wl,
                                                   float* __restrict__ biasz) {
    int k = blockIdx.x, t = threadIdx.x;
    W1p4[k * HD + t] = make_float4(W_ih1[(size_t)t * (HD + 1) + k],
                                   W_ih1[(size_t)(t + HD) * (HD + 1) + k],
                                   W_ih1[(size_t)(t + 2 * HD) * (HD + 1) + k], 0.f);
    W2p4[k * HD + t] = make_float4(W_ih2[(size_t)t * HD + k],
                                   W_ih2[(size_t)(t + HD) * HD + k],
                                   W_ih2[(size_t)(t + 2 * HD) * HD + k], 0.f);
    if (k == 0) {
#pragma unroll
        for (int c = 0; c < 3; ++c) wl[c * HD + t] = W_ih1[(size_t)(c * HD + t) * (HD + 1) + HD];
        biasz[t] = 0.f;
    }
}

// ------------- C = A(lda) @ B(ldb, K x N) + bias, K=256, 64x64 tiles -------------
__global__ __launch_bounds__(256) void gemm_bias_kernel(const float* __restrict__ A, int lda,
                                                        const float* __restrict__ Bm, int ldb,
                                                        const float* __restrict__ bias,
                                                        float* __restrict__ C, int ldc) {
    __shared__ float As[16][68];
    __shared__ float Bs[16][68];
    const int tid = threadIdx.x;
    const int tx = tid & 15, ty = tid >> 4;
    const int mBase = blockIdx.x * 64, nBase = blockIdx.y * 64;
    const int lr = tid >> 2, lc = (tid & 3) << 2;
    const int bkk = tid >> 4, bn4 = (tid & 15) << 2;
    float acc[4][4] = {};
    for (int k0 = 0; k0 < HD; k0 += 16) {
        float4 av = *(const float4*)&A[(size_t)(mBase + lr) * lda + k0 + lc];
        As[lc + 0][lr] = av.x; As[lc + 1][lr] = av.y; As[lc + 2][lr] = av.z; As[lc + 3][lr] = av.w;
        float4 bv = *(const float4*)&Bm[(size_t)(k0 + bkk) * ldb + nBase + bn4];
        *(float4*)&Bs[bkk][bn4] = bv;
        __syncthreads();
#pragma unroll
        for (int kk = 0; kk < 16; ++kk) {
            const float4 a4 = *(const float4*)&As[kk][ty << 2];
            const float4 b4 = *(const float4*)&Bs[kk][tx << 2];
            const float ar_[4] = {a4.x, a4.y, a4.z, a4.w};
            const float br_[4] = {b4.x, b4.y, b4.z, b4.w};
#pragma unroll
            for (int i = 0; i < 4; ++i)
#pragma unroll
                for (int j = 0; j < 4; ++j) acc[i][j] = fmaf(ar_[i], br_[j], acc[i][j]);
        }
        __syncthreads();
    }
#pragma unroll
    for (int i = 0; i < 4; ++i) {
        float o[4];
#pragma unroll
        for (int j = 0; j < 4; ++j) o[j] = acc[i][j] + bias[nBase + (tx << 2) + j];
        *(float4*)&C[(size_t)(mBase + (ty << 2) + i) * ldc + nBase + (tx << 2)] =
            make_float4(o[0], o[1], o[2], o[3]);
    }
}

// ---- shared helper: dst[bb][tid] = gru(src[bb] @ Wp^T + bi (+ Dv*wls), bhh) ----
// Wp pre-offset by tid. wls==nullptr -> no D term (compile-time folded after inline).
__device__ __forceinline__ void gru_phase(const float4* __restrict__ wp,
                                          const float src[4][HD],
                                          float dst[4][HD],
                                          const float* __restrict__ bi,
                                          const float* __restrict__ bhh,
                                          const float* __restrict__ wls,
                                          float Dv, int tid) {
    float acc[4][3] = {};
    for (int k = 0; k < HD; k += 8) {
        float4 wv[8];
#pragma unroll
        for (int u = 0; u < 8; ++u) wv[u] = wp[(k + u) << 8];
#pragma unroll
        for (int uu = 0; uu < 2; ++uu) {
#pragma unroll
            for (int bb = 0; bb < 4; ++bb) {
                const float4 h = *(const float4*)&src[bb][k + (uu << 2)];
                const float hv[4] = {h.x, h.y, h.z, h.w};
#pragma unroll
                for (int u = 0; u < 4; ++u) {
                    const float4 w4 = wv[(uu << 2) + u];
                    acc[bb][0] = fmaf(hv[u], w4.x, acc[bb][0]);
                    acc[bb][1] = fmaf(hv[u], w4.y, acc[bb][1]);
                    acc[bb][2] = fmaf(hv[u], w4.z, acc[bb][2]);
                }
            }
        }
    }
#pragma unroll
    for (int bb = 0; bb < 4; ++bb) {
        float gr = acc[bb][0] + bi[tid];
        float gz = acc[bb][1] + bi[tid + HD];
        float gn = acc[bb][2] + bi[tid + 2 * HD];
        if (wls != nullptr) {
            gr += Dv * wls[tid];
            gz += Dv * wls[tid + HD];
            gn += Dv * wls[tid + 2 * HD];
        }
        dst[bb][tid] = gru0(gr, gz, gn, bhh[tid], bhh[tid + HD], bhh[tid + 2 * HD]);
    }
}

// ============ fused decode: 1 kernel, 100 steps, block owns 4 b's, gi1 on the fly ============
__global__ __launch_bounds__(256) void decode_kernel(const float* __restrict__ refb,
                                                     const float* __restrict__ enc,
                                                     const float* __restrict__ meanenc,
                                                     const float4* __restrict__ W1p4,
                                                     const float4* __restrict__ W2p4,
                                                     const float* __restrict__ W_q,
                                                     const float* __restrict__ b_ih1,
                                                     const float* __restrict__ b_hh1,
                                                     const float* __restrict__ b_ih2,
                                                     const float* __restrict__ b_hh2,
                                                     const float* __restrict__ wl,
                                                     const float* __restrict__ vvec,
                                                     const float* __restrict__ x,
                                                     float* __restrict__ out) {
    __shared__ float wls[HD3], bi1s[HD3], bhh1s[HD3], bi2s[HD3], bhh2s[HD3];
    __shared__ float vs[HD];
    __shared__ float h1s[4][HD];
    __shared__ float h2s[4][HD];
    __shared__ float qs[4][HD];
    __shared__ float encs[4][HD];
    __shared__ float us[4][SEQ];
    __shared__ int   rem_s[4][SEQ];
    __shared__ int   pi_s[4][SEQ];
    __shared__ float ll_s[4];

    const int blk = blockIdx.x, tid = threadIdx.x;
    const int w = tid >> 6, lane = tid & 63;
    const int b0 = blk << 2;

#pragma unroll
    for (int s = 0; s < 3; ++s) {
        int j = s * HD + tid;
        wls[j] = wl[j];
        bi1s[j] = b_ih1[j];
        bhh1s[j] = b_hh1[j];
        bi2s[j] = b_ih2[j];
        bhh2s[j] = b_hh2[j];
    }
    vs[tid] = vvec[tid];
    if (tid < SEQ) {
#pragma unroll
        for (int bb = 0; bb < 4; ++bb) rem_s[bb][tid] = tid;
    }
    if (tid < 4) ll_s[tid] = 0.f;
#pragma unroll
    for (int bb = 0; bb < 4; ++bb) encs[bb][tid] = meanenc[(size_t)(b0 + bb) * HD + tid];
    __syncthreads();

    float Dreg = 1.0f;
    const float invN = 1.0f / SEQ;

    // t=0 context (mean), D = 1.0
    gru_phase(W1p4 + tid, encs, h1s, bi1s, bhh1s, wls, Dreg, tid);
    __syncthreads();

    for (int t = 0; t < SEQ; ++t) {
        const int cnt = SEQ - t;
        // ---- phase A: gi2 = h1 @ W2^T ; gru2 -> h2s ----
        gru_phase(W2p4 + tid, h1s, h2s, bi2s, bhh2s, nullptr, 0.f, tid);
        __syncthreads();
        // ---- phase B: q = h2 @ W_q -> qs ----
        {
            float qa[4] = {};
            const float* wq = W_q + tid;
            for (int k = 0; k < HD; k += 8) {
                float wv[8];
#pragma unroll
                for (int u = 0; u < 8; ++u) wv[u] = wq[(k + u) << 8];
#pragma unroll
                for (int uu = 0; uu < 2; ++uu) {
#pragma unroll
                    for (int bb = 0; bb < 4; ++bb) {
                        const float4 h = *(const float4*)&h2s[bb][k + (uu << 2)];
                        qa[bb] = fmaf(h.x, wv[(uu << 2) + 0], qa[bb]);
                        qa[bb] = fmaf(h.y, wv[(uu << 2) + 1], qa[bb]);
                        qa[bb] = fmaf(h.z, wv[(uu << 2) + 2], qa[bb]);
                        qa[bb] = fmaf(h.w, wv[(uu << 2) + 3], qa[bb]);
                    }
                }
            }
#pragma unroll
            for (int bb = 0; bb < 4; ++bb) qs[bb][tid] = qa[bb];
        }
        __syncthreads();
        // ---- phase C: per-wave score/argmax/softmax/update for b = b0 + w ----
        {
            const int b = b0 + w;
            const float4 qv = *(const float4*)&qs[w][lane << 2];
            const float4 vv = *(const float4*)&vs[lane << 2];
            const float* Rb = refb + (size_t)b * SEQ * HD;
            int j = 0;
            for (; j + 2 <= cnt; j += 2) {
                int n0 = rem_s[w][j], n1 = rem_s[w][j + 1];
                const float4 r0 = *(const float4*)&Rb[(size_t)n0 * HD + (lane << 2)];
                const float4 r1 = *(const float4*)&Rb[(size_t)n1 * HD + (lane << 2)];
                float s0 = tanhf(qv.x + r0.x) * vv.x;
                float s1 = tanhf(qv.x + r1.x) * vv.x;
                s0 = fmaf(tanhf(qv.y + r0.y), vv.y, s0);
                s1 = fmaf(tanhf(qv.y + r1.y), vv.y, s1);
                s0 = fmaf(tanhf(qv.z + r0.z), vv.z, s0);
                s1 = fmaf(tanhf(qv.z + r1.z), vv.z, s1);
                s0 = fmaf(tanhf(qv.w + r0.w), vv.w, s0);
                s1 = fmaf(tanhf(qv.w + r1.w), vv.w, s1);
#pragma unroll
                for (int o = 1; o < 64; o <<= 1) {
                    s0 += __shfl_xor(s0, o, 64);
                    s1 += __shfl_xor(s1, o, 64);
                }
                if (lane == 0) {
                    us[w][j] = 10.0f * tanhf(s0);
                    us[w][j + 1] = 10.0f * tanhf(s1);
                }
            }
            if (j < cnt) {
                int n0 = rem_s[w][j];
                const float4 r0 = *(const float4*)&Rb[(size_t)n0 * HD + (lane << 2)];
                float s0 = tanhf(qv.x + r0.x) * vv.x;
                s0 = fmaf(tanhf(qv.y + r0.y), vv.y, s0);
                s0 = fmaf(tanhf(qv.z + r0.z), vv.z, s0);
                s0 = fmaf(tanhf(qv.w + r0.w), vv.w, s0);
#pragma unroll
                for (int o = 1; o < 64; o <<= 1) s0 += __shfl_xor(s0, o, 64);
                if (lane == 0) us[w][j] = 10.0f * tanhf(s0);
            }
            // wave argmax (first compacted index on ties) + softmax denom
            float va = (lane < cnt) ? us[w][lane] : -3.0e38f;
            int ia = lane;
            if (lane + 64 < cnt) {
                float vb2 = us[w][lane + 64];
                if (vb2 > va) { va = vb2; ia = lane + 64; }
            }
#pragma unroll
            for (int o = 1; o < 64; o <<= 1) {
                float ov = __shfl_xor(va, o, 64);
                int oi = __shfl_xor(ia, o, 64);
                if (ov > va || (ov == va && oi < ia)) { va = ov; ia = oi; }
            }
            float e = ((lane < cnt) ? expf(us[w][lane] - va) : 0.0f) +
                      ((lane + 64 < cnt) ? expf(us[w][lane + 64] - va) : 0.0f);
#pragma unroll
            for (int o = 1; o < 64; o <<= 1) e += __shfl_xor(e, o, 64);
            const int nsel = rem_s[w][ia];     // all lanes read BEFORE lane0's swap-remove
            if (lane == 0) {
                ll_s[w] += -logf(e);           // u[sel]==max -> log_softmax[sel] = -log(sum)
                pi_s[w][t] = nsel;
                rem_s[w][ia] = rem_s[w][cnt - 1];
            }
            // gather selected encoder row for next-step gi1
            if (t < SEQ - 1) {
                const float4 ev = *(const float4*)&enc[((size_t)b * SEQ + nsel) * HD + (lane << 2)];
                *(float4*)&encs[w][lane << 2] = ev;
            }
        }
        __syncthreads();
        Dreg -= invN;
        if (t < SEQ - 1) {
            // h1 for step t+1 with D after (t+1) subtractions
            gru_phase(W1p4 + tid, encs, h1s, bi1s, bhh1s, wls, Dreg, tid);
            __syncthreads();
        }
    }

    // ---- final: tour cost + outputs (per wave, own b) ----
    {
        const int b = b0 + w;
        float d = 0.f;
        for (int e2 = lane; e2 < SEQ; e2 += 64) {
            int p = pi_s[w][e2];
            int pn = pi_s[w][(e2 == SEQ - 1) ? 0 : e2 + 1];
            float xa = x[((size_t)b * SEQ + p) * 2 + 0];
            float ya = x[((size_t)b * SEQ + p) * 2 + 1];
            float xb2 = x[((size_t)b * SEQ + pn) * 2 + 0];
            float yb2 = x[((size_t)b * SEQ + pn) * 2 + 1];
            float dx = xa - xb2, dy = ya - yb2;
            d += sqrtf(dx * dx + dy * dy);
        }
#pragma unroll
        for (int o = 1; o < 64; o <<= 1) d += __shfl_xor(d, o, 64);
        if (lane == 0) {
            out[b] = d;
            out[BATCH + b] = ll_s[w];
        }
    }
}

extern "C" void kernel_launch(void* const* d_in, const int* in_sizes, int n_in,
                              void* d_out, int out_size, void* d_ws, size_t ws_size,
                              hipStream_t stream) {
    const float* x     = (const float*)d_in[0];
    const float* enc   = (const float*)d_in[1];
    const float* W_ih1 = (const float*)d_in[2];
    // d_in[3] = W_hh1: unused (h==0 -> gh == b_hh)
    const float* b_ih1 = (const float*)d_in[4];
    const float* b_hh1 = (const float*)d_in[5];
    const float* W_ih2 = (const float*)d_in[6];
    // d_in[7] = W_hh2: unused
    const float* b_ih2 = (const float*)d_in[8];
    const float* b_hh2 = (const float*)d_in[9];
    const float* W_q   = (const float*)d_in[10];
    const float* W_ref = (const float*)d_in[11];
    const float* v     = (const float*)d_in[12];
    float* out = (float*)d_out;
    (void)in_sizes; (void)n_in; (void)out_size;

    char* w = (char*)d_ws;
    size_t off = 0;
    auto take = [&](size_t bytes) {
        char* p = w + off;
        off = (off + bytes + 255) & ~(size_t)255;
        return p;
    };
    float*  refb    = (float*)take((size_t)BATCH * SEQ * HD * 4);   // 104.9 MB
    float*  meanenc = (float*)take((size_t)BATCH * HD * 4);
    float4* W1p4    = (float4*)take((size_t)HD * HD * 16);          // 1 MB
    float4* W2p4    = (float4*)take((size_t)HD * HD * 16);          // 1 MB
    float*  wl      = (float*)take((size_t)HD3 * 4);
    float*  biasz   = (float*)take((size_t)HD * 4);
    if (ws_size < off) return;   // defensive: never write past the workspace

    hipLaunchKernelGGL(init_mean_kernel, dim3(BATCH), dim3(HD), 0, stream, enc, meanenc);
    hipLaunchKernelGGL(prep_kernel, dim3(HD), dim3(HD), 0, stream,
                       W_ih1, W_ih2, W1p4, W2p4, wl, biasz);
    // refb = enc @ W_ref   (102400 x 256 x 256)
    hipLaunchKernelGGL(gemm_bias_kernel, dim3(BATCH * SEQ / 64, HD / 64), dim3(256), 0, stream,
                       enc, HD, W_ref, HD, biasz, refb, HD);
    // one kernel = whole 100-step decode + tour cost
    hipLaunchKernelGGL(decode_kernel, dim3(BATCH / 4), dim3(256), 0, stream,
                       refb, enc, meanenc, W1p4, W2p4, W_q,
                       b_ih1, b_hh1, b_ih2, b_hh2, wl, v, x, out);
}

// Round 8
// 5456.636 us; speedup vs baseline: 1.5604x; 1.5604x over previous
//
#include <hip/hip_runtime.h>
#include <cstdint>
#include <cmath>

#define BATCH 1024
#define SEQ   100
#define HD    256
#define HD3   768
#define NTHR  512

__device__ __forceinline__ float sigmoidf_(float x) { return 1.0f / (1.0f + expf(-x)); }

// GRU cell with h=0: out = (1-z)*n ; gh == b_hh (constant)
__device__ __forceinline__ float gru0(float gr, float gz, float gn, float hr, float hz, float hn) {
    float r = sigmoidf_(gr + hr);
    float z = sigmoidf_(gz + hz);
    float n = tanhf(gn + r * hn);
    return (1.0f - z) * n;
}

// ---------------- init: mean over N of encoder rows ----------------
__global__ __launch_bounds__(256) void init_mean_kernel(const float* __restrict__ enc,
                                                        float* __restrict__ meanenc) {
    int b = blockIdx.x, tid = threadIdx.x;
    const float* e = enc + (size_t)b * SEQ * HD + tid;
    float s = 0.f;
    for (int n = 0; n < SEQ; ++n) s += e[(size_t)n * HD];
    meanenc[(size_t)b * HD + tid] = s * (1.0f / SEQ);
}

// ---- prep: per-thread float4 weight packs + wl + zero bias ----
// W1p4[k*256+t] = (W_ih1[t][k], W_ih1[t+256][k], W_ih1[t+512][k], 0)   (W_ih1 ld=257)
// W2p4[k*256+t] = (W_ih2[t][k], W_ih2[t+256][k], W_ih2[t+512][k], 0)   (W_ih2 ld=256)
__global__ __launch_bounds__(256) void prep_kernel(const float* __restrict__ W_ih1,
                                                   const float* __restrict__ W_ih2,
                                                   float4* __restrict__ W1p4,
                                                   float4* __restrict__ W2p4,
                                                   float* __restrict__ wl,
                                                   float* __restrict__ biasz) {
    int k = blockIdx.x, t = threadIdx.x;
    W1p4[k * HD + t] = make_float4(W_ih1[(size_t)t * (HD + 1) + k],
                                   W_ih1[(size_t)(t + HD) * (HD + 1) + k],
                                   W_ih1[(size_t)(t + 2 * HD) * (HD + 1) + k], 0.f);
    W2p4[k * HD + t] = make_float4(W_ih2[(size_t)t * HD + k],
                                   W_ih2[(size_t)(t + HD) * HD + k],
                                   W_ih2[(size_t)(t + 2 * HD) * HD + k], 0.f);
    if (k == 0) {
#pragma unroll
        for (int c = 0; c < 3; ++c) wl[c * HD + t] = W_ih1[(size_t)(c * HD + t) * (HD + 1) + HD];
        biasz[t] = 0.f;
    }
}

// ------------- C = A(lda) @ B(ldb, K x N) + bias, K=256, 64x64 tiles -------------
__global__ __launch_bounds__(256) void gemm_bias_kernel(const float* __restrict__ A, int lda,
                                                        const float* __restrict__ Bm, int ldb,
                                                        const float* __restrict__ bias,
                                                        float* __restrict__ C, int ldc) {
    __shared__ float As[16][68];
    __shared__ float Bs[16][68];
    const int tid = threadIdx.x;
    const int tx = tid & 15, ty = tid >> 4;
    const int mBase = blockIdx.x * 64, nBase = blockIdx.y * 64;
    const int lr = tid >> 2, lc = (tid & 3) << 2;
    const int bkk = tid >> 4, bn4 = (tid & 15) << 2;
    float acc[4][4] = {};
    for (int k0 = 0; k0 < HD; k0 += 16) {
        float4 av = *(const float4*)&A[(size_t)(mBase + lr) * lda + k0 + lc];
        As[lc + 0][lr] = av.x; As[lc + 1][lr] = av.y; As[lc + 2][lr] = av.z; As[lc + 3][lr] = av.w;
        float4 bv = *(const float4*)&Bm[(size_t)(k0 + bkk) * ldb + nBase + bn4];
        *(float4*)&Bs[bkk][bn4] = bv;
        __syncthreads();
#pragma unroll
        for (int kk = 0; kk < 16; ++kk) {
            const float4 a4 = *(const float4*)&As[kk][ty << 2];
            const float4 b4 = *(const float4*)&Bs[kk][tx << 2];
            const float ar_[4] = {a4.x, a4.y, a4.z, a4.w};
            const float br_[4] = {b4.x, b4.y, b4.z, b4.w};
#pragma unroll
            for (int i = 0; i < 4; ++i)
#pragma unroll
                for (int j = 0; j < 4; ++j) acc[i][j] = fmaf(ar_[i], br_[j], acc[i][j]);
        }
        __syncthreads();
    }
#pragma unroll
    for (int i = 0; i < 4; ++i) {
        float o[4];
#pragma unroll
        for (int j = 0; j < 4; ++j) o[j] = acc[i][j] + bias[nBase + (tx << 2) + j];
        *(float4*)&C[(size_t)(mBase + (ty << 2) + i) * ldc + nBase + (tx << 2)] =
            make_float4(o[0], o[1], o[2], o[3]);
    }
}

// ==== fused decode: 1 kernel, 100 steps, block owns 4 b's, 512 thr, split-K GEMVs ====
__global__ __launch_bounds__(512, 2) void decode_kernel(const float* __restrict__ refb,
                                                        const float* __restrict__ enc,
                                                        const float* __restrict__ meanenc,
                                                        const float4* __restrict__ W1p4,
                                                        const float4* __restrict__ W2p4,
                                                        const float* __restrict__ W_q,
                                                        const float* __restrict__ b_ih1,
                                                        const float* __restrict__ b_hh1,
                                                        const float* __restrict__ b_ih2,
                                                        const float* __restrict__ b_hh2,
                                                        const float* __restrict__ wl,
                                                        const float* __restrict__ vvec,
                                                        const float* __restrict__ x,
                                                        float* __restrict__ out) {
    __shared__ float wls[HD3], bi1s[HD3], bhh1s[HD3], bi2s[HD3], bhh2s[HD3];
    __shared__ float vs[HD];
    __shared__ float h1s[4][HD];
    __shared__ float h2s[4][HD];
    __shared__ float qs[4][HD];
    __shared__ float encs[4][HD];
    __shared__ float part[4][3][HD];     // split-K partials (kh==1 half)
    __shared__ float us[4][SEQ];
    __shared__ int   rem_s[4][SEQ];
    __shared__ int   pi_s[4][SEQ];
    __shared__ float ll_s[4];

    const int blk = blockIdx.x, tid = threadIdx.x;
    const int w = tid >> 6, lane = tid & 63;
    const int col = tid & 255, kh = tid >> 8;      // split-K: kh in {0,1}
    const int b0 = blk << 2;

    for (int j = tid; j < HD3; j += NTHR) {
        wls[j] = wl[j];
        bi1s[j] = b_ih1[j];
        bhh1s[j] = b_hh1[j];
        bi2s[j] = b_ih2[j];
        bhh2s[j] = b_hh2[j];
    }
    if (tid < HD) vs[tid] = vvec[tid];
    if (tid < SEQ) {
#pragma unroll
        for (int bb = 0; bb < 4; ++bb) rem_s[bb][tid] = tid;
    }
    if (tid < 4) ll_s[tid] = 0.f;
    for (int e = tid; e < 4 * HD; e += NTHR)
        encs[e >> 8][e & 255] = meanenc[(size_t)(b0 + (e >> 8)) * HD + (e & 255)];
    __syncthreads();

    float Dreg = 1.0f;
    const float invN = 1.0f / SEQ;

    // ---- split-K GRU phase: dst[bb][col] = gru(src[bb] @ Wp^T + bi (+Dv*wl), bhh) ----
    // generic lambda keeps LDS address space for src/dst
    auto gru_phase = [&](const float4* __restrict__ wp, auto& src, auto& dst,
                         const float* __restrict__ bi, const float* __restrict__ bhh,
                         bool useD, float Dv) {
        float acc[4][3] = {};
        const int kb = kh << 7;
        const float4* wpc = wp + ((size_t)kb << 8) + col;
        for (int k = 0; k < 128; k += 16) {
            float4 wv[16];
#pragma unroll
            for (int u = 0; u < 16; ++u) wv[u] = wpc[(size_t)(k + u) << 8];
#pragma unroll
            for (int uu = 0; uu < 4; ++uu) {
#pragma unroll
                for (int bb = 0; bb < 4; ++bb) {
                    const float4 h = *(const float4*)&src[bb][kb + k + (uu << 2)];
                    const float hv[4] = {h.x, h.y, h.z, h.w};
#pragma unroll
                    for (int u = 0; u < 4; ++u) {
                        const float4 w4 = wv[(uu << 2) + u];
                        acc[bb][0] = fmaf(hv[u], w4.x, acc[bb][0]);
                        acc[bb][1] = fmaf(hv[u], w4.y, acc[bb][1]);
                        acc[bb][2] = fmaf(hv[u], w4.z, acc[bb][2]);
                    }
                }
            }
        }
        if (kh) {
#pragma unroll
            for (int bb = 0; bb < 4; ++bb)
#pragma unroll
                for (int g = 0; g < 3; ++g) part[bb][g][col] = acc[bb][g];
        }
        __syncthreads();
        if (!kh) {
#pragma unroll
            for (int bb = 0; bb < 4; ++bb) {
                float gr = acc[bb][0] + part[bb][0][col] + bi[col];
                float gz = acc[bb][1] + part[bb][1][col] + bi[col + HD];
                float gn = acc[bb][2] + part[bb][2][col] + bi[col + 2 * HD];
                if (useD) {
                    gr += Dv * wls[col];
                    gz += Dv * wls[col + HD];
                    gn += Dv * wls[col + 2 * HD];
                }
                dst[bb][col] = gru0(gr, gz, gn, bhh[col], bhh[col + HD], bhh[col + 2 * HD]);
            }
        }
    };

    // t=0 context (mean), D = 1.0
    gru_phase(W1p4, encs, h1s, bi1s, bhh1s, true, Dreg);
    __syncthreads();

    for (int t = 0; t < SEQ; ++t) {
        const int cnt = SEQ - t;
        // ---- phase A: h2 = gru2(h1 @ W2^T + b_ih2) ----
        gru_phase(W2p4, h1s, h2s, bi2s, bhh2s, false, 0.f);
        __syncthreads();
        // ---- phase B: q = h2 @ W_q (split-K) ----
        {
            float qa[4] = {};
            const int kb = kh << 7;
            const float* wqc = W_q + ((size_t)kb << 8) + col;
            for (int k = 0; k < 128; k += 16) {
                float wv[16];
#pragma unroll
                for (int u = 0; u < 16; ++u) wv[u] = wqc[(size_t)(k + u) << 8];
#pragma unroll
                for (int uu = 0; uu < 4; ++uu) {
#pragma unroll
                    for (int bb = 0; bb < 4; ++bb) {
                        const float4 h = *(const float4*)&h2s[bb][kb + k + (uu << 2)];
                        qa[bb] = fmaf(h.x, wv[(uu << 2) + 0], qa[bb]);
                        qa[bb] = fmaf(h.y, wv[(uu << 2) + 1], qa[bb]);
                        qa[bb] = fmaf(h.z, wv[(uu << 2) + 2], qa[bb]);
                        qa[bb] = fmaf(h.w, wv[(uu << 2) + 3], qa[bb]);
                    }
                }
            }
            if (kh) {
#pragma unroll
                for (int bb = 0; bb < 4; ++bb) part[bb][0][col] = qa[bb];
            }
            __syncthreads();
            if (!kh) {
#pragma unroll
                for (int bb = 0; bb < 4; ++bb) qs[bb][col] = qa[bb] + part[bb][0][col];
            }
        }
        __syncthreads();
        // ---- phase C: scoring, 2 waves per b (row parity), prefetched ref rows ----
        {
            const int bq = w & 3;                  // batch slot
            const int half = w >> 2;               // row parity
            const int b = b0 + bq;
            const float4 qv = *(const float4*)&qs[bq][lane << 2];
            const float4 vv = *(const float4*)&vs[lane << 2];
            const float* Rb = refb + (size_t)b * SEQ * HD;
            int j = half;
            float4 rcur = make_float4(0.f, 0.f, 0.f, 0.f);
            if (j < cnt)
                rcur = *(const float4*)&Rb[(size_t)rem_s[bq][j] * HD + (lane << 2)];
            while (j < cnt) {
                const int jn = j + 2;
                float4 rnext = make_float4(0.f, 0.f, 0.f, 0.f);
                if (jn < cnt)
                    rnext = *(const float4*)&Rb[(size_t)rem_s[bq][jn] * HD + (lane << 2)];
                float s0 = tanhf(qv.x + rcur.x) * vv.x;
                s0 = fmaf(tanhf(qv.y + rcur.y), vv.y, s0);
                s0 = fmaf(tanhf(qv.z + rcur.z), vv.z, s0);
                s0 = fmaf(tanhf(qv.w + rcur.w), vv.w, s0);
#pragma unroll
                for (int o = 1; o < 64; o <<= 1) s0 += __shfl_xor(s0, o, 64);
                if (lane == 0) us[bq][j] = 10.0f * tanhf(s0);
                rcur = rnext;
                j = jn;
            }
        }
        __syncthreads();
        // ---- argmax + log-softmax + state update + enc gather (waves 0..3, b = b0+w) ----
        if (w < 4) {
            const int b = b0 + w;
            float va = (lane < cnt) ? us[w][lane] : -3.0e38f;
            int ia = lane;
            if (lane + 64 < cnt) {
                float vb2 = us[w][lane + 64];
                if (vb2 > va) { va = vb2; ia = lane + 64; }
            }
#pragma unroll
            for (int o = 1; o < 64; o <<= 1) {
                float ov = __shfl_xor(va, o, 64);
                int oi = __shfl_xor(ia, o, 64);
                if (ov > va || (ov == va && oi < ia)) { va = ov; ia = oi; }
            }
            float e = ((lane < cnt) ? expf(us[w][lane] - va) : 0.0f) +
                      ((lane + 64 < cnt) ? expf(us[w][lane + 64] - va) : 0.0f);
#pragma unroll
            for (int o = 1; o < 64; o <<= 1) e += __shfl_xor(e, o, 64);
            const int nsel = rem_s[w][ia];        // all lanes read BEFORE lane0's swap-remove
            if (lane == 0) {
                ll_s[w] += -logf(e);              // u[sel]==max -> log_softmax[sel] = -log(sum)
                pi_s[w][t] = nsel;
                rem_s[w][ia] = rem_s[w][cnt - 1];
            }
            if (t < SEQ - 1) {
                const float4 ev = *(const float4*)&enc[((size_t)b * SEQ + nsel) * HD + (lane << 2)];
                *(float4*)&encs[w][lane << 2] = ev;
            }
        }
        __syncthreads();
        Dreg -= invN;
        if (t < SEQ - 1) {
            // h1 for step t+1 with D after (t+1) subtractions
            gru_phase(W1p4, encs, h1s, bi1s, bhh1s, true, Dreg);
            __syncthreads();
        }
    }

    // ---- final: tour cost + outputs (waves 0..3, own b) ----
    if (w < 4) {
        const int b = b0 + w;
        float d = 0.f;
        for (int e2 = lane; e2 < SEQ; e2 += 64) {
            int p = pi_s[w][e2];
            int pn = pi_s[w][(e2 == SEQ - 1) ? 0 : e2 + 1];
            float xa = x[((size_t)b * SEQ + p) * 2 + 0];
            float ya = x[((size_t)b * SEQ + p) * 2 + 1];
            float xb2 = x[((size_t)b * SEQ + pn) * 2 + 0];
            float yb2 = x[((size_t)b * SEQ + pn) * 2 + 1];
            float dx = xa - xb2, dy = ya - yb2;
            d += sqrtf(dx * dx + dy * dy);
        }
#pragma unroll
        for (int o = 1; o < 64; o <<= 1) d += __shfl_xor(d, o, 64);
        if (lane == 0) {
            out[b] = d;
            out[BATCH + b] = ll_s[w];
        }
    }
}

extern "C" void kernel_launch(void* const* d_in, const int* in_sizes, int n_in,
                              void* d_out, int out_size, void* d_ws, size_t ws_size,
                              hipStream_t stream) {
    const float* x     = (const float*)d_in[0];
    const float* enc   = (const float*)d_in[1];
    const float* W_ih1 = (const float*)d_in[2];
    // d_in[3] = W_hh1: unused (h==0 -> gh == b_hh)
    const float* b_ih1 = (const float*)d_in[4];
    const float* b_hh1 = (const float*)d_in[5];
    const float* W_ih2 = (const float*)d_in[6];
    // d_in[7] = W_hh2: unused
    const float* b_ih2 = (const float*)d_in[8];
    const float* b_hh2 = (const float*)d_in[9];
    const float* W_q   = (const float*)d_in[10];
    const float* W_ref = (const float*)d_in[11];
    const float* v     = (const float*)d_in[12];
    float* out = (float*)d_out;
    (void)in_sizes; (void)n_in; (void)out_size;

    char* w = (char*)d_ws;
    size_t off = 0;
    auto take = [&](size_t bytes) {
        char* p = w + off;
        off = (off + bytes + 255) & ~(size_t)255;
        return p;
    };
    float*  refb    = (float*)take((size_t)BATCH * SEQ * HD * 4);   // 104.9 MB
    float*  meanenc = (float*)take((size_t)BATCH * HD * 4);
    float4* W1p4    = (float4*)take((size_t)HD * HD * 16);          // 1 MB
    float4* W2p4    = (float4*)take((size_t)HD * HD * 16);          // 1 MB
    float*  wl      = (float*)take((size_t)HD3 * 4);
    float*  biasz   = (float*)take((size_t)HD * 4);
    if (ws_size < off) return;   // defensive: never write past the workspace

    hipLaunchKernelGGL(init_mean_kernel, dim3(BATCH), dim3(HD), 0, stream, enc, meanenc);
    hipLaunchKernelGGL(prep_kernel, dim3(HD), dim3(HD), 0, stream,
                       W_ih1, W_ih2, W1p4, W2p4, wl, biasz);
    // refb = enc @ W_ref   (102400 x 256 x 256)
    hipLaunchKernelGGL(gemm_bias_kernel, dim3(BATCH * SEQ / 64, HD / 64), dim3(256), 0, stream,
                       enc, HD, W_ref, HD, biasz, refb, HD);
    // one kernel = whole 100-step decode + tour cost
    hipLaunchKernelGGL(decode_kernel, dim3(BATCH / 4), dim3(NTHR), 0, stream,
                       refb, enc, meanenc, W1p4, W2p4, W_q,
                       b_ih1, b_hh1, b_ih2, b_hh2, wl, v, x, out);
}